// Round 5
// baseline (226.201 us; speedup 1.0000x reference)
//
#include <hip/hip_runtime.h>
#include <math.h>

#define DEVI __device__ __forceinline__

constexpr int B = 2, P = 16, G = 128, E = 96, N = 128, CO = 2;
constexpr int NBLK = 256;   // == CU count; 1 block/CU (LDS ~96KB) -> all resident

DEVI float lrelu(float x) { return x > 0.f ? x : 0.01f * x; }

// ---- workspace layout (floats) ----
constexpr int OFF_U1     = 0;                       // B*N*P*G = 524288
constexpr int OFF_V1     = OFF_U1 + 524288;         // B*N*G*E = 3145728
constexpr int OFF_MAXPU0 = OFF_V1 + 3145728;        // B*N*G = 32768
constexpr int OFF_MAXEV0 = OFF_MAXPU0 + 32768;      // 32768
constexpr int OFF_MP110  = OFF_MAXEV0 + 32768;      // 32768 (== me011)
constexpr int OFF_MG110  = OFF_MP110 + 32768;       // B*N*P = 4096
constexpr int OFF_S001A  = OFF_MG110 + 4096;        // B*N*E = 24576 (== mg011)
constexpr int OFF_RMP    = OFF_S001A + 24576;       // B*4*G = 1024
constexpr int OFF_RMG    = OFF_RMP + 1024;          // B*4*P = 128
constexpr int OFF_RME    = OFF_RMG + 128;           // B*2*G = 512
constexpr int OFF_RMG011 = OFF_RME + 512;           // B*2*E = 384
constexpr int OFF_C1P    = OFF_RMG011 + 384;        // 4096
constexpr int OFF_BF1G   = OFF_C1P + 4096;          // 32768
constexpr int OFF_EG1E   = OFF_BF1G + 32768;        // 24576
constexpr int OFF_M110   = OFF_EG1E + 24576;        // 4096
constexpr int OFF_M011E  = OFF_M110 + 4096;         // 24576
constexpr int OFF_S001B  = OFF_M011E + 24576;       // 24576
constexpr int OFF_CTR    = OFF_S001B + 24576;       // 4 x u32 barrier counters

// ---- shared memory union (max ~96KB -> 1 block/CU) ----
union alignas(16) SharedU {
  struct {                                   // phase A (layer0)
    float xs[4 * 16 * 128];                  // 32KB
    float v0[128 * 97];                      // 49.7KB
    float u0[16 * 128];                      // 8KB
    float rmp[512], rmgS[64], rme[256], rmg011L[192];
    float mpu[128], mev[128], part[256];
  } a;
  struct {                                   // phase C (layer1)
    float s110c[128 * 16];                   // 8KB
    float s011c[128 * 96];                   // 48KB
    float W0L110[1536], W0L011[768], W0L001[128];
    float busum[128], bvsum[128], mpu[128], mev[128];
    float x011row[192], rmg011s[192], x001s[96];
    float x110col[64], rmg110p[64], rmp4[4], rme2[2];
  } c;
  struct {                                   // phase D (post1)
    float vrow[128 * 97];                    // 49.7KB
    float uU[16 * 128];
    float part[256];
    float smaxeV[128], smaxpU[128];
  } d;
  struct {                                   // phase E (final)
    float sm011[128], sm001[128], scp[16], sce[96], srow[16], scol[96];
  } e;
};

DEVI void grid_sync(unsigned* ctr) {
  __syncthreads();
  if (threadIdx.x == 0) {
    __threadfence();                         // release (agent scope)
    atomicAdd(ctr, 1u);
    while (__hip_atomic_load(ctr, __ATOMIC_RELAXED, __HIP_MEMORY_SCOPE_AGENT)
           < (unsigned)NBLK) {
      __builtin_amdgcn_s_sleep(1);
    }
  }
  __syncthreads();
  __threadfence();                           // acquire (agent scope)
}

__global__ void __launch_bounds__(256) k_fused(
    const float* __restrict__ x110, const float* __restrict__ x011,
    const float* __restrict__ x001,
    const float* __restrict__ W0_110, const float* __restrict__ b0_110,
    const float* __restrict__ W0_011, const float* __restrict__ b0_011,
    const float* __restrict__ W0_001, const float* __restrict__ b0_001,
    const float* __restrict__ W1, const float* __restrict__ b1,
    const float* __restrict__ Wact, const float* __restrict__ bact,
    const float* __restrict__ Wcrit, const float* __restrict__ bcrit,
    float* __restrict__ out, float* __restrict__ w, unsigned* __restrict__ ctrs) {
  __shared__ SharedU sh;
  const int blk = blockIdx.x, tid = threadIdx.x;

  float* U1      = w + OFF_U1;
  float* V1      = w + OFF_V1;
  float* maxpU0g = w + OFF_MAXPU0;
  float* maxeV0g = w + OFF_MAXEV0;
  float* mp110   = w + OFF_MP110;
  float* mg110   = w + OFF_MG110;
  float* s001a   = w + OFF_S001A;
  float* rmpG    = w + OFF_RMP;
  float* rmgG    = w + OFF_RMG;
  float* rmeG    = w + OFF_RME;
  float* rmg011G = w + OFF_RMG011;
  float* C1p     = w + OFF_C1P;
  float* BF1g    = w + OFF_BF1G;
  float* EG1e    = w + OFF_EG1E;
  float* m110    = w + OFF_M110;
  float* m011e   = w + OFF_M011E;
  float* s001b   = w + OFF_S001B;

  // ======================= PHASE A: layer 0, bn = blk =======================
  {
    const int bn = blk, b = bn >> 7, n = bn & 127;
    {
      const float4* xsrc = (const float4*)(x110 + (size_t)b * 8192);
      float4* xdst = (float4*)sh.a.xs;
#pragma unroll
      for (int k = 0; k < 8; k++) xdst[tid + k * 256] = xsrc[tid + k * 256];
    }
    __syncthreads();
    for (int i = tid; i < 512; i += 256) {       // rmp[c][g] = max_p x110
      int c = i >> 7, g = i & 127;
      float m = -INFINITY;
      for (int p = 0; p < P; p++) m = fmaxf(m, sh.a.xs[(c * 16 + p) * 128 + g]);
      sh.a.rmp[i] = m;
    }
    if (tid < 64) {                              // rmgS[c][p] = max_g x110
      int c = tid >> 4, p = tid & 15;
      float m = -INFINITY;
      for (int g = 0; g < G; g++) m = fmaxf(m, sh.a.xs[(c * 16 + p) * 128 + g]);
      sh.a.rmgS[tid] = m;
    }
    {                                            // rme[c][g] = max_e x011
      int c = tid >> 7, g = tid & 127;
      const float4* r = (const float4*)(x011 + ((size_t)(b * 2 + c) * 128 + g) * 96);
      float m = -INFINITY;
#pragma unroll
      for (int j = 0; j < 24; j++) {
        float4 v = r[j];
        m = fmaxf(m, fmaxf(fmaxf(v.x, v.y), fmaxf(v.z, v.w)));
      }
      sh.a.rme[tid] = m;
    }
    if (tid < 192) {                             // rmg011L[c][e] = max_g x011
      int c = tid / 96, e = tid % 96;
      const float* pp = x011 + ((size_t)(b * 2 + c) * 128) * 96 + e;
      float m = -INFINITY;
      for (int g = 0; g < G; g++) m = fmaxf(m, pp[g * 96]);
      sh.a.rmg011L[tid] = m;
    }
    __syncthreads();
    float w0[4], w1[4], w2[4];
#pragma unroll
    for (int cc = 0; cc < 4; cc++) {
      w0[cc] = W0_110[n * 4 + cc];
      w1[cc] = W0_110[512 + n * 4 + cc];
      w2[cc] = W0_110[1024 + n * 4 + cc];
    }
    float we0 = W0_011[512 + n * 2], we1 = W0_011[512 + n * 2 + 1];
    float bu = b0_110[n] + b0_110[128 + n] + b0_110[256 + n] + b0_011[256 + n];
    float vw00 = W0_011[n * 2], vw01 = W0_011[n * 2 + 1];
    float vw10 = W0_011[256 + n * 2], vw11 = W0_011[256 + n * 2 + 1];
    float w001 = W0_001[n];
    float bv = b0_011[n] + b0_011[128 + n] + b0_001[n];

#pragma unroll
    for (int k = 0; k < 8; k++) {                // U0 row
      int i = tid + k * 256, p = i >> 7, g = i & 127;
      float acc = bu + we0 * sh.a.rme[g] + we1 * sh.a.rme[128 + g];
#pragma unroll
      for (int cc = 0; cc < 4; cc++)
        acc += w0[cc] * sh.a.xs[(cc * 16 + p) * 128 + g]
             + w1[cc] * sh.a.rmp[cc * 128 + g]
             + w2[cc] * sh.a.rmgS[cc * 16 + p];
      sh.a.u0[i] = acc;
    }
    {                                            // V0 row
      const float* xa = x011 + (size_t)(b * 2) * 12288;
      const float* xb = xa + 12288;
      const float* xc = x001 + b * 96;
      for (int k = 0; k < 48; k++) {
        int i = tid + k * 256;
        int g = i / 96, e = i - g * 96;
        float val = bv + vw00 * xa[i] + vw01 * xb[i]
                  + vw10 * sh.a.rmg011L[e] + vw11 * sh.a.rmg011L[96 + e]
                  + w001 * xc[e];
        sh.a.v0[g * 97 + e] = val;
      }
    }
    __syncthreads();
    if (tid < 128) {                             // maxpU
      float m = -INFINITY;
      for (int p = 0; p < P; p++) m = fmaxf(m, sh.a.u0[p * 128 + tid]);
      sh.a.mpu[tid] = m;
      maxpU0g[bn * 128 + tid] = m;
    }
    {                                            // maxeV partials
      int g = tid & 127, h = tid >> 7;
      const float* r = &sh.a.v0[g * 97 + h * 48];
      float m = -INFINITY;
      for (int j = 0; j < 48; j++) m = fmaxf(m, r[j]);
      sh.a.part[tid] = m;
    }
    __syncthreads();
    if (tid < 128) {
      float m = fmaxf(sh.a.part[tid], sh.a.part[128 + tid]);
      sh.a.mev[tid] = m;
      maxeV0g[bn * 128 + tid] = m;
      mp110[bn * 128 + tid] = lrelu(sh.a.mpu[tid] + m);   // == me011
    }
    __syncthreads();
    {                                            // mg110 partials
      int p = tid >> 4, ch = tid & 15;
      float m = -INFINITY;
      for (int g = ch * 8; g < ch * 8 + 8; g++)
        m = fmaxf(m, sh.a.u0[p * 128 + g] + sh.a.mev[g]);
      sh.a.part[tid] = m;
    }
    if (tid < 96) {                              // s001a (== mg011)
      float m = -INFINITY;
      for (int g = 0; g < G; g++) m = fmaxf(m, sh.a.mpu[g] + sh.a.v0[g * 97 + tid]);
      s001a[bn * 96 + tid] = lrelu(m);
    }
    __syncthreads();
    if (tid < 16) {
      float m = -INFINITY;
      for (int ch = 0; ch < 16; ch++) m = fmaxf(m, sh.a.part[tid * 16 + ch]);
      mg110[bn * 16 + tid] = lrelu(m);
    }
    if (n == 0) {                                // publish tiny rm arrays
      for (int i = tid; i < 512; i += 256) rmpG[b * 512 + i] = sh.a.rmp[i];
      if (tid < 64) rmgG[b * 64 + tid] = sh.a.rmgS[tid];
      rmeG[b * 256 + tid] = sh.a.rme[tid];
      if (tid < 192) rmg011G[b * 192 + tid] = sh.a.rmg011L[tid];
    }
  }
  grid_sync(&ctrs[0]);

  // ======================= PHASE B: small GEMMs =======================
  {
    int t = blk * 256 + tid;
    if (t < 4096) {                      // C1p = W1[2] @ mg110
      int p = t & 15, n = (t >> 4) & 127, b = t >> 11;
      float acc = 0.f;
      for (int c = 0; c < N; c++)
        acc += W1[(2 * N + n) * N + c] * mg110[(b * N + c) * P + p];
      C1p[t] = acc;
    } else if (t < 36864) {              // BF1g = (W1[1]+W1[5]) @ mp110
      int i = t - 4096;
      int g = i & 127, n = (i >> 7) & 127, b = i >> 14;
      float acc = 0.f;
      for (int c = 0; c < N; c++)
        acc += (W1[(1 * N + n) * N + c] + W1[(5 * N + n) * N + c])
               * mp110[(b * N + c) * G + g];
      BF1g[i] = acc;
    } else if (t < 61440) {              // EG1e = (W1[4]+W1[6]) @ s001a
      int i = t - 36864;
      int e = i % 96; int r = i / 96; int n = r & 127, b = r >> 7;
      float acc = 0.f;
      for (int c = 0; c < N; c++)
        acc += (W1[(4 * N + n) * N + c] + W1[(6 * N + n) * N + c])
               * s001a[(b * N + c) * E + e];
      EG1e[i] = acc;
    }
  }
  grid_sync(&ctrs[1]);

  // ======================= PHASE C: layer 1, blk = (b,g) =======================
  {
    const int b = blk >> 7, g = blk & 127;
    for (int i = tid; i < 1536; i += 256) sh.c.W0L110[i] = W0_110[i];
    for (int i = tid; i < 768; i += 256) sh.c.W0L011[i] = W0_011[i];
    if (tid < 128) {
      sh.c.W0L001[tid] = W0_001[tid];
      sh.c.busum[tid] = b0_110[tid] + b0_110[128 + tid] + b0_110[256 + tid]
                      + b0_011[256 + tid];
      sh.c.bvsum[tid] = b0_011[tid] + b0_011[128 + tid] + b0_001[tid];
      sh.c.mpu[tid] = maxpU0g[(b * 128 + tid) * 128 + g];
      sh.c.mev[tid] = maxeV0g[(b * 128 + tid) * 128 + g];
    }
    if (tid < 192) {
      int c = tid / 96, e = tid % 96;
      sh.c.x011row[tid] = x011[((size_t)(b * 2 + c) * 128 + g) * 96 + e];
      sh.c.rmg011s[tid] = rmg011G[b * 192 + tid];
    }
    if (tid < 96) sh.c.x001s[tid] = x001[b * 96 + tid];
    if (tid < 64) {
      int c = tid >> 4, p = tid & 15;
      sh.c.x110col[tid] = x110[((size_t)(b * 4 + c) * 16 + p) * 128 + g];
      sh.c.rmg110p[tid] = rmgG[b * 64 + tid];
    }
    if (tid < 4) sh.c.rmp4[tid] = rmpG[(b * 4 + tid) * 128 + g];
    if (tid < 2) sh.c.rme2[tid] = rmeG[(b * 2 + tid) * 128 + g];
    __syncthreads();

    // s110 column (c,p) at this g
#pragma unroll
    for (int k = 0; k < 8; k++) {
      int i = tid + k * 256, c = i >> 4, p = i & 15;
      float acc = sh.c.busum[c] + sh.c.W0L011[512 + c * 2] * sh.c.rme2[0]
                + sh.c.W0L011[512 + c * 2 + 1] * sh.c.rme2[1];
#pragma unroll
      for (int cc = 0; cc < 4; cc++)
        acc += sh.c.W0L110[c * 4 + cc] * sh.c.x110col[cc * 16 + p]
             + sh.c.W0L110[512 + c * 4 + cc] * sh.c.rmp4[cc]
             + sh.c.W0L110[1024 + c * 4 + cc] * sh.c.rmg110p[cc * 16 + p];
      sh.c.s110c[i] = lrelu(acc + sh.c.mev[c]);
    }
    // s011 column (c,e) at this g
    for (int k = 0; k < 48; k++) {
      int i = tid + k * 256;
      int c = i / 96, e = i - c * 96;
      float v = sh.c.bvsum[c]
              + sh.c.W0L011[c * 2] * sh.c.x011row[e]
              + sh.c.W0L011[c * 2 + 1] * sh.c.x011row[96 + e]
              + sh.c.W0L011[256 + c * 2] * sh.c.rmg011s[e]
              + sh.c.W0L011[256 + c * 2 + 1] * sh.c.rmg011s[96 + e]
              + sh.c.W0L001[c] * sh.c.x001s[e];
      sh.c.s011c[i] = lrelu(v + sh.c.mpu[c]);
    }
    __syncthreads();

    // ---- U1: thread = (n = tid&127, p-half = tid>>7), 8 p each ----
    {
      int n = tid & 127, ph = tid >> 7;
      float bb = b1[n] + b1[128 + n] + b1[256 + n] + b1[640 + n]
               + BF1g[(b * 128 + n) * 128 + g];
      const float* cp = &C1p[(b * 128 + n) * 16 + ph * 8];
      float a[8];
#pragma unroll
      for (int j = 0; j < 8; j++) a[j] = bb + cp[j];
      const float* wr = W1 + (size_t)n * 128;
      for (int c = 0; c < 128; c++) {
        float wv = wr[c];
        float4 s0 = *(const float4*)&sh.c.s110c[c * 16 + ph * 8];
        float4 s1 = *(const float4*)&sh.c.s110c[c * 16 + ph * 8 + 4];
        a[0] += wv * s0.x; a[1] += wv * s0.y; a[2] += wv * s0.z; a[3] += wv * s0.w;
        a[4] += wv * s1.x; a[5] += wv * s1.y; a[6] += wv * s1.z; a[7] += wv * s1.w;
      }
      float* dst = U1 + ((size_t)(b * 128 + n) * 16 + ph * 8) * 128 + g;
#pragma unroll
      for (int j = 0; j < 8; j++) dst[j * 128] = a[j];
    }
    // ---- V1: thread = (4n, 12e), K=128 ----
    {
      int n0 = (tid >> 3) * 4, e0 = (tid & 7) * 12;
      float4 acc[4][3];
#pragma unroll
      for (int ni = 0; ni < 4; ni++) {
        int n = n0 + ni;
        float bbv = b1[384 + n] + b1[512 + n] + b1[768 + n];
        const float* eg = EG1e + (b * 128 + n) * 96 + e0;
#pragma unroll
        for (int k = 0; k < 3; k++)
          acc[ni][k] = make_float4(bbv + eg[k * 4], bbv + eg[k * 4 + 1],
                                   bbv + eg[k * 4 + 2], bbv + eg[k * 4 + 3]);
      }
      const float* wA = W1 + (size_t)(384 + n0) * 128;
      for (int c = 0; c < 128; c += 4) {
        float4 wv[4];
#pragma unroll
        for (int ni = 0; ni < 4; ni++)
          wv[ni] = *(const float4*)&wA[ni * 128 + c];
#pragma unroll
        for (int cc = 0; cc < 4; cc++) {
          float4 s0 = *(const float4*)&sh.c.s011c[(c + cc) * 96 + e0];
          float4 s1 = *(const float4*)&sh.c.s011c[(c + cc) * 96 + e0 + 4];
          float4 s2 = *(const float4*)&sh.c.s011c[(c + cc) * 96 + e0 + 8];
#pragma unroll
          for (int ni = 0; ni < 4; ni++) {
            float wc = cc == 0 ? wv[ni].x : cc == 1 ? wv[ni].y
                     : cc == 2 ? wv[ni].z : wv[ni].w;
            acc[ni][0].x += wc * s0.x; acc[ni][0].y += wc * s0.y;
            acc[ni][0].z += wc * s0.z; acc[ni][0].w += wc * s0.w;
            acc[ni][1].x += wc * s1.x; acc[ni][1].y += wc * s1.y;
            acc[ni][1].z += wc * s1.z; acc[ni][1].w += wc * s1.w;
            acc[ni][2].x += wc * s2.x; acc[ni][2].y += wc * s2.y;
            acc[ni][2].z += wc * s2.z; acc[ni][2].w += wc * s2.w;
          }
        }
      }
#pragma unroll
      for (int ni = 0; ni < 4; ni++) {
        float* dst = V1 + ((size_t)(b * 128 + n0 + ni) * 128 + g) * 96 + e0;
#pragma unroll
        for (int k = 0; k < 3; k++) *(float4*)(dst + k * 4) = acc[ni][k];
      }
    }
  }
  grid_sync(&ctrs[2]);

  // ======================= PHASE D: post1, bn = blk =======================
  {
    const int bn = blk;
    const float4* usrc = (const float4*)(U1 + (size_t)bn * 2048);
    ((float4*)sh.d.uU)[tid] = usrc[tid];
    ((float4*)sh.d.uU)[tid + 256] = usrc[tid + 256];
    const float4* vsrc = (const float4*)(V1 + (size_t)bn * 12288);
#pragma unroll
    for (int k = 0; k < 12; k++) {
      int i4 = tid + k * 256;
      float4 v = vsrc[i4];
      int c = i4 / 24, e0 = (i4 - c * 24) * 4;
      float* d = &sh.d.vrow[c * 97 + e0];
      d[0] = v.x; d[1] = v.y; d[2] = v.z; d[3] = v.w;
    }
    __syncthreads();
    {                                            // maxeV partials
      int g = tid & 127, h = tid >> 7;
      const float* r = &sh.d.vrow[g * 97 + h * 48];
      float m = -INFINITY;
      for (int j = 0; j < 48; j++) m = fmaxf(m, r[j]);
      sh.d.part[tid] = m;
    }
    __syncthreads();
    if (tid < 128) {
      sh.d.smaxeV[tid] = fmaxf(sh.d.part[tid], sh.d.part[tid + 128]);
      float mp = -INFINITY;
      for (int p = 0; p < P; p++) mp = fmaxf(mp, sh.d.uU[p * 128 + tid]);
      sh.d.smaxpU[tid] = mp;
    }
    __syncthreads();
    if (tid >= 128 && tid < 144) {   // m110 (wave 2, parallel with below)
      int p = tid - 128;
      float s = 0.f;
      for (int g = 0; g < G; g++)
        s += lrelu(sh.d.uU[p * 128 + g] + sh.d.smaxeV[g]);
      m110[bn * 16 + p] = s * (1.f / G);
    }
    if (tid < 96) {                  // m011e / s001b (waves 0-1)
      float s = 0.f, mm = -INFINITY;
      for (int g = 0; g < G; g++) {
        float pre = sh.d.smaxpU[g] + sh.d.vrow[g * 97 + tid];
        s += lrelu(pre);
        mm = fmaxf(mm, pre);
      }
      m011e[bn * 96 + tid] = s * (1.f / G);
      s001b[bn * 96 + tid] = lrelu(mm);
    }
  }
  grid_sync(&ctrs[3]);

  // ======================= PHASE E: heads, blk < 4 =======================
  if (blk < 4) {
    const int o = blk & 1, b = blk >> 1;
    const int t = tid;
    if (t < 128) {
      float s1 = 0.f, s2 = 0.f;
      const float* p1 = m011e + (b * N + t) * E;
      const float* p2 = s001b + (b * N + t) * E;
      for (int e = 0; e < E; e++) { s1 += p1[e]; s2 += p2[e]; }
      sh.e.sm011[t] = s1 * (1.f / E);
      sh.e.sm001[t] = s2 * (1.f / E);
    }
    __syncthreads();
    if (t < P) {
      const float* wa0 = Wact + o * N;
      const float* wa1 = Wact + (1 * CO + o) * N;
      const float* wa2 = Wact + (2 * CO + o) * N;
      const float* wc0 = Wcrit + o * N;
      float a = 0.f, c = 0.f, aa = 0.f;
      for (int n = 0; n < N; n++) {
        float m = m110[(b * N + n) * P + t];
        a += wa0[n] * m;
        c += wc0[n] * m;
        aa += wa1[n] * sh.e.sm011[n] + wa2[n] * sh.e.sm001[n];
      }
      float act = a + aa + bact[o] + bact[CO + o] + bact[2 * CO + o];
      out[(b * CO + o) * P + t] = lrelu(act);
      sh.e.scp[t] = c + bcrit[o];
    } else if (t < P + E) {
      int e = t - P;
      const float* wc1 = Wcrit + (1 * CO + o) * N;
      const float* wc2 = Wcrit + (2 * CO + o) * N;
      float c = 0.f;
      for (int n = 0; n < N; n++)
        c += wc1[n] * m011e[(b * N + n) * E + e]
           + wc2[n] * s001b[(b * N + n) * E + e];
      sh.e.sce[e] = c + bcrit[CO + o] + bcrit[2 * CO + o];
    }
    __syncthreads();
    if (t < P) {
      float m = -INFINITY;
      for (int e = 0; e < E; e++) m = fmaxf(m, lrelu(sh.e.scp[t] + sh.e.sce[e]));
      sh.e.srow[t] = m;
    } else if (t < P + E) {
      int e = t - P;
      float m = -INFINITY;
      for (int p = 0; p < P; p++) m = fmaxf(m, lrelu(sh.e.scp[p] + sh.e.sce[e]));
      sh.e.scol[e] = m;
    }
    __syncthreads();
    if (t == 0) {
      float v110 = 0.f, v011 = 0.f;
      for (int p = 0; p < P; p++) v110 += sh.e.srow[p];
      for (int e = 0; e < E; e++) v011 += sh.e.scol[e];
      out[B * CO * P + b * CO + o] = 2.f + v110 + 2.f * v011;
    }
  }
}

extern "C" void kernel_launch(void* const* d_in, const int* in_sizes, int n_in,
                              void* d_out, int out_size, void* d_ws, size_t ws_size,
                              hipStream_t stream) {
  const float* x110   = (const float*)d_in[0];
  const float* x011   = (const float*)d_in[1];
  const float* x001   = (const float*)d_in[2];
  const float* W0_110 = (const float*)d_in[3];
  const float* b0_110 = (const float*)d_in[4];
  const float* W0_011 = (const float*)d_in[5];
  const float* b0_011 = (const float*)d_in[6];
  const float* W0_001 = (const float*)d_in[7];
  const float* b0_001 = (const float*)d_in[8];
  const float* W1     = (const float*)d_in[9];
  const float* b1     = (const float*)d_in[10];
  const float* Wact   = (const float*)d_in[11];
  const float* bact   = (const float*)d_in[12];
  const float* Wcrit  = (const float*)d_in[13];
  const float* bcrit  = (const float*)d_in[14];
  float* out = (float*)d_out;
  float* w = (float*)d_ws;
  unsigned* ctrs = (unsigned*)(w + OFF_CTR);

  hipMemsetAsync(ctrs, 0, 4 * sizeof(unsigned), stream);
  k_fused<<<NBLK, 256, 0, stream>>>(x110, x011, x001, W0_110, b0_110, W0_011,
                                    b0_011, W0_001, b0_001, W1, b1,
                                    Wact, bact, Wcrit, bcrit, out, w, ctrs);
}

// Round 6
// 162.807 us; speedup vs baseline: 1.3894x; 1.3894x over previous
//
#include <hip/hip_runtime.h>
#include <math.h>

#define DEVI __device__ __forceinline__

constexpr int B = 2, P = 16, G = 128, E = 96, N = 128, CO = 2;

DEVI float lrelu(float x) { return x > 0.f ? x : 0.01f * x; }

// ---- workspace layout (floats) ----
// U1: [b][g][p][n]  (coalesced writes in layer1: lanes = n)
// V1: [b][g][n][e]  (coalesced writes: wave covers 32n x 96e contiguous)
constexpr int OFF_U1     = 0;                       // 524288
constexpr int OFF_V1     = OFF_U1 + 524288;         // 3145728
constexpr int OFF_MAXPU0 = OFF_V1 + 3145728;        // B*N*G = 32768
constexpr int OFF_MAXEV0 = OFF_MAXPU0 + 32768;      // 32768
constexpr int OFF_MP110  = OFF_MAXEV0 + 32768;      // 32768 (== me011)
constexpr int OFF_MG110  = OFF_MP110 + 32768;       // B*N*P = 4096
constexpr int OFF_S001A  = OFF_MG110 + 4096;        // B*N*E = 24576 (== mg011)
constexpr int OFF_RMP    = OFF_S001A + 24576;       // 1024
constexpr int OFF_RMG    = OFF_RMP + 1024;          // 128
constexpr int OFF_RME    = OFF_RMG + 128;           // 512
constexpr int OFF_RMG011 = OFF_RME + 512;           // 384
constexpr int OFF_M110   = OFF_RMG011 + 384;        // 4096
constexpr int OFF_M011E  = OFF_M110 + 4096;         // 24576
constexpr int OFF_S001B  = OFF_M011E + 24576;       // 24576
constexpr int OFF_WT     = OFF_S001B + 24576;       // 5*16384 = 81920
// wT[m][c][n]: m0=W1[0]^T, m1=(W1[1]+W1[5])^T, m2=W1[2]^T, m3=W1[3]^T, m4=(W1[4]+W1[6])^T

// ---------------------------------------------------------------------------
// K1: fused layer 0, one block per (b,n) [R4-proven] + W1 transpose tail.
__global__ void __launch_bounds__(256) k_layer0(
    const float* __restrict__ x110, const float* __restrict__ x011,
    const float* __restrict__ x001,
    const float* __restrict__ W0_110, const float* __restrict__ b0_110,
    const float* __restrict__ W0_011, const float* __restrict__ b0_011,
    const float* __restrict__ W0_001, const float* __restrict__ b0_001,
    const float* __restrict__ W1,
    float* __restrict__ maxpU0g, float* __restrict__ maxeV0g,
    float* __restrict__ mp110, float* __restrict__ mg110,
    float* __restrict__ s001a,
    float* __restrict__ rmpG, float* __restrict__ rmgG,
    float* __restrict__ rmeG, float* __restrict__ rmg011G,
    float* __restrict__ wT) {
  __shared__ float xs[4 * 16 * 128];
  __shared__ float v0[128 * 97];
  __shared__ float u0[16 * 128];
  __shared__ float rmp[512], rmgS[64], rme[256], rmg011L[192];
  __shared__ float mpu[128], mev[128], part[256];
  const int bn = blockIdx.x, b = bn >> 7, n = bn & 127, tid = threadIdx.x;

  {
    const float4* xsrc = (const float4*)(x110 + (size_t)b * 8192);
    float4* xdst = (float4*)xs;
#pragma unroll
    for (int k = 0; k < 8; k++) xdst[tid + k * 256] = xsrc[tid + k * 256];
  }
  __syncthreads();
  for (int i = tid; i < 512; i += 256) {
    int c = i >> 7, g = i & 127;
    float m = -INFINITY;
    for (int p = 0; p < P; p++) m = fmaxf(m, xs[(c * 16 + p) * 128 + g]);
    rmp[i] = m;
  }
  if (tid < 64) {
    int c = tid >> 4, p = tid & 15;
    float m = -INFINITY;
    for (int g = 0; g < G; g++) m = fmaxf(m, xs[(c * 16 + p) * 128 + g]);
    rmgS[tid] = m;
  }
  {
    int c = tid >> 7, g = tid & 127;
    const float4* r = (const float4*)(x011 + ((size_t)(b * 2 + c) * 128 + g) * 96);
    float m = -INFINITY;
#pragma unroll
    for (int j = 0; j < 24; j++) {
      float4 v = r[j];
      m = fmaxf(m, fmaxf(fmaxf(v.x, v.y), fmaxf(v.z, v.w)));
    }
    rme[tid] = m;
  }
  if (tid < 192) {
    int c = tid / 96, e = tid % 96;
    const float* pp = x011 + ((size_t)(b * 2 + c) * 128) * 96 + e;
    float m = -INFINITY;
    for (int g = 0; g < G; g++) m = fmaxf(m, pp[g * 96]);
    rmg011L[tid] = m;
  }
  __syncthreads();
  float w0[4], w1[4], w2[4];
#pragma unroll
  for (int cc = 0; cc < 4; cc++) {
    w0[cc] = W0_110[n * 4 + cc];
    w1[cc] = W0_110[512 + n * 4 + cc];
    w2[cc] = W0_110[1024 + n * 4 + cc];
  }
  float we0 = W0_011[512 + n * 2], we1 = W0_011[512 + n * 2 + 1];
  float bu = b0_110[n] + b0_110[128 + n] + b0_110[256 + n] + b0_011[256 + n];
  float vw00 = W0_011[n * 2], vw01 = W0_011[n * 2 + 1];
  float vw10 = W0_011[256 + n * 2], vw11 = W0_011[256 + n * 2 + 1];
  float w001 = W0_001[n];
  float bv = b0_011[n] + b0_011[128 + n] + b0_001[n];

#pragma unroll
  for (int k = 0; k < 8; k++) {
    int i = tid + k * 256, p = i >> 7, g = i & 127;
    float acc = bu + we0 * rme[g] + we1 * rme[128 + g];
#pragma unroll
    for (int cc = 0; cc < 4; cc++)
      acc += w0[cc] * xs[(cc * 16 + p) * 128 + g] + w1[cc] * rmp[cc * 128 + g]
           + w2[cc] * rmgS[cc * 16 + p];
    u0[i] = acc;
  }
  {
    const float* xa = x011 + (size_t)(b * 2) * 12288;
    const float* xb = xa + 12288;
    const float* xc = x001 + b * 96;
    for (int k = 0; k < 48; k++) {
      int i = tid + k * 256;
      int g = i / 96, e = i - g * 96;
      float val = bv + vw00 * xa[i] + vw01 * xb[i]
                + vw10 * rmg011L[e] + vw11 * rmg011L[96 + e] + w001 * xc[e];
      v0[g * 97 + e] = val;
    }
  }
  __syncthreads();
  if (tid < 128) {
    float m = -INFINITY;
    for (int p = 0; p < P; p++) m = fmaxf(m, u0[p * 128 + tid]);
    mpu[tid] = m;
    maxpU0g[bn * 128 + tid] = m;
  }
  {
    int g = tid & 127, h = tid >> 7;
    const float* r = &v0[g * 97 + h * 48];
    float m = -INFINITY;
    for (int j = 0; j < 48; j++) m = fmaxf(m, r[j]);
    part[tid] = m;
  }
  __syncthreads();
  if (tid < 128) {
    float m = fmaxf(part[tid], part[128 + tid]);
    mev[tid] = m;
    maxeV0g[bn * 128 + tid] = m;
    mp110[bn * 128 + tid] = lrelu(mpu[tid] + m);
  }
  __syncthreads();
  {
    int p = tid >> 4, ch = tid & 15;
    float m = -INFINITY;
    for (int g = ch * 8; g < ch * 8 + 8; g++)
      m = fmaxf(m, u0[p * 128 + g] + mev[g]);
    part[tid] = m;
  }
  if (tid < 96) {
    float m = -INFINITY;
    for (int g = 0; g < G; g++) m = fmaxf(m, mpu[g] + v0[g * 97 + tid]);
    s001a[bn * 96 + tid] = lrelu(m);
  }
  __syncthreads();
  if (tid < 16) {
    float m = -INFINITY;
    for (int ch = 0; ch < 16; ch++) m = fmaxf(m, part[tid * 16 + ch]);
    mg110[bn * 16 + tid] = lrelu(m);
  }
  if (n == 0) {
    for (int i = tid; i < 512; i += 256) rmpG[b * 512 + i] = rmp[i];
    if (tid < 64) rmgG[b * 64 + tid] = rmgS[tid];
    rmeG[b * 256 + tid] = rme[tid];
    if (tid < 192) rmg011G[b * 192 + tid] = rmg011L[tid];
  }
  // ---- W1 transpose/fold tail: wT[m][c][n] ----
  {
    const int gt = bn * 256 + tid;
#pragma unroll
    for (int it = 0; it < 2; it++) {
      int idx = gt + it * 65536;
      if (idx < 81920) {
        int m = idx >> 14, r = idx & 16383;
        int c = r >> 7, nn = r & 127;
        float v;
        if (m == 0)      v = W1[nn * 128 + c];
        else if (m == 1) v = W1[16384 + nn * 128 + c] + W1[5 * 16384 + nn * 128 + c];
        else if (m == 2) v = W1[2 * 16384 + nn * 128 + c];
        else if (m == 3) v = W1[3 * 16384 + nn * 128 + c];
        else             v = W1[4 * 16384 + nn * 128 + c] + W1[6 * 16384 + nn * 128 + c];
        wT[idx] = v;
      }
    }
  }
}

// ---------------------------------------------------------------------------
// K2: fused layer 1 + inlined small GEMMs. One block per (b,g), full n.
__global__ void __launch_bounds__(256) k_layer1b(
    const float* __restrict__ x110, const float* __restrict__ x011,
    const float* __restrict__ x001,
    const float* __restrict__ W0_110, const float* __restrict__ b0_110,
    const float* __restrict__ W0_011, const float* __restrict__ b0_011,
    const float* __restrict__ W0_001, const float* __restrict__ b0_001,
    const float* __restrict__ maxpU0g, const float* __restrict__ maxeV0g,
    const float* __restrict__ rmpG, const float* __restrict__ rmgG,
    const float* __restrict__ rmeG, const float* __restrict__ rmg011G,
    const float* __restrict__ mp110, const float* __restrict__ mg110,
    const float* __restrict__ s001a,
    const float* __restrict__ wT, const float* __restrict__ b1,
    float* __restrict__ U1, float* __restrict__ V1) {
  __shared__ float s110c[128 * 16];        // (c,p)  8KB
  __shared__ float s011c[128 * 96];        // (c,e)  48KB
  __shared__ float sA[128 * 96];           // s001a[b] (c,e)  48KB
  __shared__ float W0L110[1536], W0L011[768], W0L001[128];
  __shared__ float busum[128], bvsum[128], mpu[128], mev[128];
  __shared__ float x011row[192], rmg011s[192], x001s[96];
  __shared__ float x110col[64], rmg110p[64], rmp4[4], rme2[2];
  const int blk = blockIdx.x;
  const int b = blk >> 7, g = blk & 127;
  const int tid = threadIdx.x;

  for (int i = tid; i < 1536; i += 256) W0L110[i] = W0_110[i];
  for (int i = tid; i < 768; i += 256) W0L011[i] = W0_011[i];
  {                                        // stage s001a[b] (coalesced f4)
    const float4* src = (const float4*)(s001a + (size_t)b * 12288);
    float4* dst = (float4*)sA;
#pragma unroll
    for (int k = 0; k < 12; k++) dst[tid + k * 256] = src[tid + k * 256];
  }
  if (tid < 128) {
    W0L001[tid] = W0_001[tid];
    busum[tid] = b0_110[tid] + b0_110[128 + tid] + b0_110[256 + tid]
               + b0_011[256 + tid];
    bvsum[tid] = b0_011[tid] + b0_011[128 + tid] + b0_001[tid];
    mpu[tid] = maxpU0g[(b * 128 + tid) * 128 + g];
    mev[tid] = maxeV0g[(b * 128 + tid) * 128 + g];
  }
  if (tid < 192) {
    int c = tid / 96, e = tid % 96;
    x011row[tid] = x011[((size_t)(b * 2 + c) * 128 + g) * 96 + e];
    rmg011s[tid] = rmg011G[b * 192 + tid];
  }
  if (tid < 96) x001s[tid] = x001[b * 96 + tid];
  if (tid < 64) {
    int c = tid >> 4, p = tid & 15;
    x110col[tid] = x110[((size_t)(b * 4 + c) * 16 + p) * 128 + g];
    rmg110p[tid] = rmgG[b * 64 + tid];
  }
  if (tid < 4) rmp4[tid] = rmpG[(b * 4 + tid) * 128 + g];
  if (tid < 2) rme2[tid] = rmeG[(b * 2 + tid) * 128 + g];
  __syncthreads();

  // s110 column (c,p) at this g   [R5-proven]
#pragma unroll
  for (int k = 0; k < 8; k++) {
    int i = tid + k * 256, c = i >> 4, p = i & 15;
    float acc = busum[c] + W0L011[512 + c * 2] * rme2[0]
              + W0L011[512 + c * 2 + 1] * rme2[1];
#pragma unroll
    for (int cc = 0; cc < 4; cc++)
      acc += W0L110[c * 4 + cc] * x110col[cc * 16 + p]
           + W0L110[512 + c * 4 + cc] * rmp4[cc]
           + W0L110[1024 + c * 4 + cc] * rmg110p[cc * 16 + p];
    s110c[i] = lrelu(acc + mev[c]);
  }
  // s011 column (c,e) at this g   [R5-proven]
  for (int k = 0; k < 48; k++) {
    int i = tid + k * 256;
    int c = i / 96, e = i - c * 96;
    float v = bvsum[c]
            + W0L011[c * 2] * x011row[e] + W0L011[c * 2 + 1] * x011row[96 + e]
            + W0L011[256 + c * 2] * rmg011s[e]
            + W0L011[256 + c * 2 + 1] * rmg011s[96 + e]
            + W0L001[c] * x001s[e];
    s011c[i] = lrelu(v + mpu[c]);
  }
  __syncthreads();

  const float* w0T  = wT;
  const float* w15T = wT + 16384;
  const float* w2T  = wT + 2 * 16384;
  const float* w3T  = wT + 3 * 16384;
  const float* w46T = wT + 4 * 16384;

  // ---- U1 cluster: n = tid&127 (lane-contiguous), ph = tid>>7 (wave-uniform)
  {
    int n = tid & 127, ph = tid >> 7;
    float bfv = 0.f;
    float a[8];
#pragma unroll
    for (int j = 0; j < 8; j++) a[j] = 0.f;
    float cp[8];
#pragma unroll
    for (int j = 0; j < 8; j++) cp[j] = 0.f;
    for (int c = 0; c < 128; c++) {
      float w0v = w0T[c * 128 + n];
      float w15v = w15T[c * 128 + n];
      float w2v = w2T[c * 128 + n];
      bfv += w15v * mp110[(b * 128 + c) * 128 + g];
      const float* mgr = &mg110[(b * 128 + c) * 16 + ph * 8];
      const float* sr = &s110c[c * 16 + ph * 8];
#pragma unroll
      for (int j = 0; j < 8; j++) {
        cp[j] += w2v * mgr[j];
        a[j] += w0v * sr[j];
      }
    }
    float bb = b1[n] + b1[128 + n] + b1[256 + n] + b1[640 + n] + bfv;
    float* dst = U1 + ((size_t)((b * 128 + g) * 16 + ph * 8)) * 128 + n;
#pragma unroll
    for (int j = 0; j < 8; j++) dst[j * 128] = a[j] + bb + cp[j];
  }
  // ---- V1 cluster (+inlined EG): n0 = (tid>>3)*4, e0 = (tid&7)*12
  {
    int n0 = (tid >> 3) * 4, e0 = (tid & 7) * 12;
    float4 acc[4][3];
#pragma unroll
    for (int ni = 0; ni < 4; ni++) {
      float bbv = b1[384 + n0 + ni] + b1[512 + n0 + ni] + b1[768 + n0 + ni];
#pragma unroll
      for (int k = 0; k < 3; k++) acc[ni][k] = make_float4(bbv, bbv, bbv, bbv);
    }
    for (int c = 0; c < 128; c++) {
      float4 w3v = *(const float4*)&w3T[c * 128 + n0];
      float4 w46v = *(const float4*)&w46T[c * 128 + n0];
      float4 s0 = *(const float4*)&s011c[c * 96 + e0];
      float4 s1 = *(const float4*)&s011c[c * 96 + e0 + 4];
      float4 s2 = *(const float4*)&s011c[c * 96 + e0 + 8];
      float4 t0 = *(const float4*)&sA[c * 96 + e0];
      float4 t1 = *(const float4*)&sA[c * 96 + e0 + 4];
      float4 t2 = *(const float4*)&sA[c * 96 + e0 + 8];
#pragma unroll
      for (int ni = 0; ni < 4; ni++) {
        float wa = ni == 0 ? w3v.x : ni == 1 ? w3v.y : ni == 2 ? w3v.z : w3v.w;
        float wb = ni == 0 ? w46v.x : ni == 1 ? w46v.y : ni == 2 ? w46v.z : w46v.w;
        acc[ni][0].x += wa * s0.x + wb * t0.x; acc[ni][0].y += wa * s0.y + wb * t0.y;
        acc[ni][0].z += wa * s0.z + wb * t0.z; acc[ni][0].w += wa * s0.w + wb * t0.w;
        acc[ni][1].x += wa * s1.x + wb * t1.x; acc[ni][1].y += wa * s1.y + wb * t1.y;
        acc[ni][1].z += wa * s1.z + wb * t1.z; acc[ni][1].w += wa * s1.w + wb * t1.w;
        acc[ni][2].x += wa * s2.x + wb * t2.x; acc[ni][2].y += wa * s2.y + wb * t2.y;
        acc[ni][2].z += wa * s2.z + wb * t2.z; acc[ni][2].w += wa * s2.w + wb * t2.w;
      }
    }
#pragma unroll
    for (int ni = 0; ni < 4; ni++) {
      float* dst = V1 + ((size_t)((b * 128 + g) * 128 + n0 + ni)) * 96 + e0;
#pragma unroll
      for (int k = 0; k < 3; k++) *(float4*)(dst + k * 4) = acc[ni][k];
    }
  }
}

// ---------------------------------------------------------------------------
// K3: per-(b,n) reduction to head inputs. U1[b][g][p][n], V1[b][g][n][e].
__global__ void __launch_bounds__(256) k_post1(
    const float* __restrict__ U1, const float* __restrict__ V1,
    float* __restrict__ m110, float* __restrict__ m011e,
    float* __restrict__ s001b) {
  __shared__ float vrow[128 * 97];
  __shared__ float uU[16 * 128];           // (p,g)
  __shared__ float part[256];
  __shared__ float smaxeV[128], smaxpU[128];
  const int bn = blockIdx.x, b = bn >> 7, n = bn & 127;
  const int tid = threadIdx.x;
  for (int i = tid; i < 2048; i += 256) {
    int p = i >> 7, g = i & 127;
    uU[i] = U1[((size_t)((b * 128 + g) * 16 + p)) * 128 + n];
  }
#pragma unroll
  for (int k = 0; k < 12; k++) {
    int i4 = tid + k * 256;
    int g = i4 / 24, e4 = i4 - g * 24;
    float4 v = *(const float4*)(V1 + ((size_t)((b * 128 + g) * 128 + n)) * 96 + e4 * 4);
    float* d = &vrow[g * 97 + e4 * 4];
    d[0] = v.x; d[1] = v.y; d[2] = v.z; d[3] = v.w;
  }
  __syncthreads();
  {
    int g = tid & 127, h = tid >> 7;
    const float* r = &vrow[g * 97 + h * 48];
    float m = -INFINITY;
    for (int j = 0; j < 48; j++) m = fmaxf(m, r[j]);
    part[tid] = m;
  }
  __syncthreads();
  if (tid < 128) {
    smaxeV[tid] = fmaxf(part[tid], part[tid + 128]);
    float mp = -INFINITY;
    for (int p = 0; p < P; p++) mp = fmaxf(mp, uU[p * 128 + tid]);
    smaxpU[tid] = mp;
  }
  __syncthreads();
  if (tid >= 128 && tid < 144) {
    int p = tid - 128;
    float s = 0.f;
    for (int g = 0; g < G; g++)
      s += lrelu(uU[p * 128 + g] + smaxeV[g]);
    m110[bn * 16 + p] = s * (1.f / G);
  }
  if (tid < 96) {
    float s = 0.f, mm = -INFINITY;
    for (int g = 0; g < G; g++) {
      float pre = smaxpU[g] + vrow[g * 97 + tid];
      s += lrelu(pre);
      mm = fmaxf(mm, pre);
    }
    m011e[bn * 96 + tid] = s * (1.f / G);
    s001b[bn * 96 + tid] = lrelu(mm);
  }
}

// ---------------------------------------------------------------------------
// K4: heads. one block per (b,o), 128 threads.  [proven]
__global__ void __launch_bounds__(128) k_final(const float* __restrict__ m110,
                                               const float* __restrict__ m011e,
                                               const float* __restrict__ s001,
                                               const float* __restrict__ Wact,
                                               const float* __restrict__ bact,
                                               const float* __restrict__ Wcrit,
                                               const float* __restrict__ bcrit,
                                               float* __restrict__ out) {
  __shared__ float sm011[N], sm001[N], scp[P], sce[E], srow[P], scol[E];
  const int bo = blockIdx.x;
  const int o = bo & 1, b = bo >> 1;
  const int t = threadIdx.x;
  {
    float s1 = 0.f, s2 = 0.f;
    const float* p1 = m011e + (b * N + t) * E;
    const float* p2 = s001 + (b * N + t) * E;
    for (int e = 0; e < E; e++) { s1 += p1[e]; s2 += p2[e]; }
    sm011[t] = s1 * (1.f / E);
    sm001[t] = s2 * (1.f / E);
  }
  __syncthreads();
  if (t < P) {
    const float* wa0 = Wact + o * N;
    const float* wa1 = Wact + (1 * CO + o) * N;
    const float* wa2 = Wact + (2 * CO + o) * N;
    const float* wc0 = Wcrit + o * N;
    float a = 0.f, c = 0.f, aa = 0.f;
    for (int n = 0; n < N; n++) {
      float m = m110[(b * N + n) * P + t];
      a += wa0[n] * m;
      c += wc0[n] * m;
      aa += wa1[n] * sm011[n] + wa2[n] * sm001[n];
    }
    float act = a + aa + bact[o] + bact[CO + o] + bact[2 * CO + o];
    out[(b * CO + o) * P + t] = lrelu(act);
    scp[t] = c + bcrit[o];
  } else if (t < P + E) {
    int e = t - P;
    const float* wc1 = Wcrit + (1 * CO + o) * N;
    const float* wc2 = Wcrit + (2 * CO + o) * N;
    float c = 0.f;
    for (int n = 0; n < N; n++)
      c += wc1[n] * m011e[(b * N + n) * E + e] + wc2[n] * s001[(b * N + n) * E + e];
    sce[e] = c + bcrit[CO + o] + bcrit[2 * CO + o];
  }
  __syncthreads();
  if (t < P) {
    float m = -INFINITY;
    for (int e = 0; e < E; e++) m = fmaxf(m, lrelu(scp[t] + sce[e]));
    srow[t] = m;
  } else if (t < P + E) {
    int e = t - P;
    float m = -INFINITY;
    for (int p = 0; p < P; p++) m = fmaxf(m, lrelu(scp[p] + sce[e]));
    scol[e] = m;
  }
  __syncthreads();
  if (t == 0) {
    float v110 = 0.f, v011 = 0.f;
    for (int p = 0; p < P; p++) v110 += srow[p];
    for (int e = 0; e < E; e++) v011 += scol[e];
    out[B * CO * P + b * CO + o] = 2.f + v110 + 2.f * v011;
  }
}

extern "C" void kernel_launch(void* const* d_in, const int* in_sizes, int n_in,
                              void* d_out, int out_size, void* d_ws, size_t ws_size,
                              hipStream_t stream) {
  const float* x110   = (const float*)d_in[0];
  const float* x011   = (const float*)d_in[1];
  const float* x001   = (const float*)d_in[2];
  const float* W0_110 = (const float*)d_in[3];
  const float* b0_110 = (const float*)d_in[4];
  const float* W0_011 = (const float*)d_in[5];
  const float* b0_011 = (const float*)d_in[6];
  const float* W0_001 = (const float*)d_in[7];
  const float* b0_001 = (const float*)d_in[8];
  const float* W1     = (const float*)d_in[9];
  const float* b1     = (const float*)d_in[10];
  const float* Wact   = (const float*)d_in[11];
  const float* bact   = (const float*)d_in[12];
  const float* Wcrit  = (const float*)d_in[13];
  const float* bcrit  = (const float*)d_in[14];
  float* out = (float*)d_out;
  float* w = (float*)d_ws;

  float* U1     = w + OFF_U1;
  float* V1     = w + OFF_V1;
  float* maxpU0 = w + OFF_MAXPU0;
  float* maxeV0 = w + OFF_MAXEV0;
  float* mp110  = w + OFF_MP110;
  float* mg110  = w + OFF_MG110;
  float* s001a  = w + OFF_S001A;
  float* rmpG   = w + OFF_RMP;
  float* rmgG   = w + OFF_RMG;
  float* rmeG   = w + OFF_RME;
  float* rmg011 = w + OFF_RMG011;
  float* m110   = w + OFF_M110;
  float* m011e  = w + OFF_M011E;
  float* s001b  = w + OFF_S001B;
  float* wT     = w + OFF_WT;

  k_layer0<<<256, 256, 0, stream>>>(x110, x011, x001, W0_110, b0_110, W0_011,
                                    b0_011, W0_001, b0_001, W1,
                                    maxpU0, maxeV0, mp110, mg110, s001a,
                                    rmpG, rmgG, rmeG, rmg011, wT);
  k_layer1b<<<256, 256, 0, stream>>>(x110, x011, x001, W0_110, b0_110, W0_011,
                                     b0_011, W0_001, b0_001,
                                     maxpU0, maxeV0, rmpG, rmgG, rmeG, rmg011,
                                     mp110, mg110, s001a, wT, b1, U1, V1);
  k_post1<<<256, 256, 0, stream>>>(U1, V1, m110, m011e, s001b);
  k_final<<<4, 128, 0, stream>>>(m110, m011e, s001b, Wact, bact, Wcrit, bcrit, out);
}

// Round 7
// 108.543 us; speedup vs baseline: 2.0840x; 1.4999x over previous
//
#include <hip/hip_runtime.h>
#include <math.h>

#define DEVI __device__ __forceinline__

constexpr int B = 2, P = 16, G = 128, E = 96, N = 128, CO = 2;

DEVI float lrelu(float x) { return x > 0.f ? x : 0.01f * x; }

// ---- workspace layout (floats) ----
// U1: [b][g][p][n]   V1: [b][g][n][e]   (both written raw, biases added in post1)
constexpr int OFF_U1     = 0;                       // 524288
constexpr int OFF_V1     = OFF_U1 + 524288;         // 3145728
constexpr int OFF_MAXPU0 = OFF_V1 + 3145728;        // 32768
constexpr int OFF_MAXEV0 = OFF_MAXPU0 + 32768;      // 32768
constexpr int OFF_MP110  = OFF_MAXEV0 + 32768;      // 32768 (== me011)
constexpr int OFF_MG110  = OFF_MP110 + 32768;       // 4096
constexpr int OFF_S001A  = OFF_MG110 + 4096;        // 24576 (== mg011)
constexpr int OFF_RMP    = OFF_S001A + 24576;       // 1024
constexpr int OFF_RMG    = OFF_RMP + 1024;          // 128
constexpr int OFF_RME    = OFF_RMG + 128;           // 512
constexpr int OFF_RMG011 = OFF_RME + 512;           // 384
constexpr int OFF_M110   = OFF_RMG011 + 384;        // 4096
constexpr int OFF_M011E  = OFF_M110 + 4096;         // 24576
constexpr int OFF_S001B  = OFF_M011E + 24576;       // 24576
constexpr int OFF_WT     = OFF_S001B + 24576;       // 5*16384
// wT[m][c][n]: m0=W1[0]^T, m1=(W1[1]+W1[5])^T, m2=W1[2]^T, m3=W1[3]^T, m4=(W1[4]+W1[6])^T

// ---------------------------------------------------------------------------
// K1: fused layer 0, one block per (b,n) [R4/R6-proven] + W1 transpose tail.
__global__ void __launch_bounds__(256) k_layer0(
    const float* __restrict__ x110, const float* __restrict__ x011,
    const float* __restrict__ x001,
    const float* __restrict__ W0_110, const float* __restrict__ b0_110,
    const float* __restrict__ W0_011, const float* __restrict__ b0_011,
    const float* __restrict__ W0_001, const float* __restrict__ b0_001,
    const float* __restrict__ W1,
    float* __restrict__ maxpU0g, float* __restrict__ maxeV0g,
    float* __restrict__ mp110, float* __restrict__ mg110,
    float* __restrict__ s001a,
    float* __restrict__ rmpG, float* __restrict__ rmgG,
    float* __restrict__ rmeG, float* __restrict__ rmg011G,
    float* __restrict__ wT) {
  __shared__ float xs[4 * 16 * 128];
  __shared__ float v0[128 * 97];
  __shared__ float u0[16 * 128];
  __shared__ float rmp[512], rmgS[64], rme[256], rmg011L[192];
  __shared__ float mpu[128], mev[128], part[256];
  const int bn = blockIdx.x, b = bn >> 7, n = bn & 127, tid = threadIdx.x;

  {
    const float4* xsrc = (const float4*)(x110 + (size_t)b * 8192);
    float4* xdst = (float4*)xs;
#pragma unroll
    for (int k = 0; k < 8; k++) xdst[tid + k * 256] = xsrc[tid + k * 256];
  }
  __syncthreads();
  for (int i = tid; i < 512; i += 256) {
    int c = i >> 7, g = i & 127;
    float m = -INFINITY;
    for (int p = 0; p < P; p++) m = fmaxf(m, xs[(c * 16 + p) * 128 + g]);
    rmp[i] = m;
  }
  if (tid < 64) {
    int c = tid >> 4, p = tid & 15;
    float m = -INFINITY;
    for (int g = 0; g < G; g++) m = fmaxf(m, xs[(c * 16 + p) * 128 + g]);
    rmgS[tid] = m;
  }
  {
    int c = tid >> 7, g = tid & 127;
    const float4* r = (const float4*)(x011 + ((size_t)(b * 2 + c) * 128 + g) * 96);
    float m = -INFINITY;
#pragma unroll
    for (int j = 0; j < 24; j++) {
      float4 v = r[j];
      m = fmaxf(m, fmaxf(fmaxf(v.x, v.y), fmaxf(v.z, v.w)));
    }
    rme[tid] = m;
  }
  if (tid < 192) {
    int c = tid / 96, e = tid % 96;
    const float* pp = x011 + ((size_t)(b * 2 + c) * 128) * 96 + e;
    float m = -INFINITY;
    for (int g = 0; g < G; g++) m = fmaxf(m, pp[g * 96]);
    rmg011L[tid] = m;
  }
  __syncthreads();
  float w0[4], w1[4], w2[4];
#pragma unroll
  for (int cc = 0; cc < 4; cc++) {
    w0[cc] = W0_110[n * 4 + cc];
    w1[cc] = W0_110[512 + n * 4 + cc];
    w2[cc] = W0_110[1024 + n * 4 + cc];
  }
  float we0 = W0_011[512 + n * 2], we1 = W0_011[512 + n * 2 + 1];
  float bu = b0_110[n] + b0_110[128 + n] + b0_110[256 + n] + b0_011[256 + n];
  float vw00 = W0_011[n * 2], vw01 = W0_011[n * 2 + 1];
  float vw10 = W0_011[256 + n * 2], vw11 = W0_011[256 + n * 2 + 1];
  float w001 = W0_001[n];
  float bv = b0_011[n] + b0_011[128 + n] + b0_001[n];

#pragma unroll
  for (int k = 0; k < 8; k++) {
    int i = tid + k * 256, p = i >> 7, g = i & 127;
    float acc = bu + we0 * rme[g] + we1 * rme[128 + g];
#pragma unroll
    for (int cc = 0; cc < 4; cc++)
      acc += w0[cc] * xs[(cc * 16 + p) * 128 + g] + w1[cc] * rmp[cc * 128 + g]
           + w2[cc] * rmgS[cc * 16 + p];
    u0[i] = acc;
  }
  {
    const float* xa = x011 + (size_t)(b * 2) * 12288;
    const float* xb = xa + 12288;
    const float* xc = x001 + b * 96;
    for (int k = 0; k < 48; k++) {
      int i = tid + k * 256;
      int g = i / 96, e = i - g * 96;
      float val = bv + vw00 * xa[i] + vw01 * xb[i]
                + vw10 * rmg011L[e] + vw11 * rmg011L[96 + e] + w001 * xc[e];
      v0[g * 97 + e] = val;
    }
  }
  __syncthreads();
  if (tid < 128) {
    float m = -INFINITY;
    for (int p = 0; p < P; p++) m = fmaxf(m, u0[p * 128 + tid]);
    mpu[tid] = m;
    maxpU0g[bn * 128 + tid] = m;
  }
  {
    int g = tid & 127, h = tid >> 7;
    const float* r = &v0[g * 97 + h * 48];
    float m = -INFINITY;
    for (int j = 0; j < 48; j++) m = fmaxf(m, r[j]);
    part[tid] = m;
  }
  __syncthreads();
  if (tid < 128) {
    float m = fmaxf(part[tid], part[128 + tid]);
    mev[tid] = m;
    maxeV0g[bn * 128 + tid] = m;
    mp110[bn * 128 + tid] = lrelu(mpu[tid] + m);
  }
  __syncthreads();
  {
    int p = tid >> 4, ch = tid & 15;
    float m = -INFINITY;
    for (int g = ch * 8; g < ch * 8 + 8; g++)
      m = fmaxf(m, u0[p * 128 + g] + mev[g]);
    part[tid] = m;
  }
  if (tid < 96) {
    float m = -INFINITY;
    for (int g = 0; g < G; g++) m = fmaxf(m, mpu[g] + v0[g * 97 + tid]);
    s001a[bn * 96 + tid] = lrelu(m);
  }
  __syncthreads();
  if (tid < 16) {
    float m = -INFINITY;
    for (int ch = 0; ch < 16; ch++) m = fmaxf(m, part[tid * 16 + ch]);
    mg110[bn * 16 + tid] = lrelu(m);
  }
  if (n == 0) {
    for (int i = tid; i < 512; i += 256) rmpG[b * 512 + i] = rmp[i];
    if (tid < 64) rmgG[b * 64 + tid] = rmgS[tid];
    rmeG[b * 256 + tid] = rme[tid];
    if (tid < 192) rmg011G[b * 192 + tid] = rmg011L[tid];
  }
  // ---- W1 transpose/fold tail: wT[m][c][n] ----
  {
    const int gt = bn * 256 + tid;
#pragma unroll
    for (int it = 0; it < 2; it++) {
      int idx = gt + it * 65536;
      if (idx < 81920) {
        int m = idx >> 14, r = idx & 16383;
        int c = r >> 7, nn = r & 127;
        float v;
        if (m == 0)      v = W1[nn * 128 + c];
        else if (m == 1) v = W1[16384 + nn * 128 + c] + W1[5 * 16384 + nn * 128 + c];
        else if (m == 2) v = W1[2 * 16384 + nn * 128 + c];
        else if (m == 3) v = W1[3 * 16384 + nn * 128 + c];
        else             v = W1[4 * 16384 + nn * 128 + c] + W1[6 * 16384 + nn * 128 + c];
        wT[idx] = v;
      }
    }
  }
}

// ---------------------------------------------------------------------------
// K2: layer 1 PURE GEMMs only. One block per (b,g), 512 threads (2 waves/SIMD).
__global__ void __launch_bounds__(512) k_layer1c(
    const float* __restrict__ x110, const float* __restrict__ x011,
    const float* __restrict__ x001,
    const float* __restrict__ W0_110, const float* __restrict__ b0_110,
    const float* __restrict__ W0_011, const float* __restrict__ b0_011,
    const float* __restrict__ W0_001, const float* __restrict__ b0_001,
    const float* __restrict__ maxpU0g, const float* __restrict__ maxeV0g,
    const float* __restrict__ rmpG, const float* __restrict__ rmgG,
    const float* __restrict__ rmeG, const float* __restrict__ rmg011G,
    const float* __restrict__ wT,
    float* __restrict__ U1, float* __restrict__ V1) {
  __shared__ float s110c[128 * 16];        // (c,p)  8KB
  __shared__ float s011c[128 * 96];        // (c,e)  48KB
  __shared__ float W0L110[1536], W0L011[768], W0L001[128];
  __shared__ float busum[128], bvsum[128], mpu[128], mev[128];
  __shared__ float x011row[192], rmg011s[192], x001s[96];
  __shared__ float x110col[64], rmg110p[64], rmp4[4], rme2[2];
  const int blk = blockIdx.x;
  const int b = blk >> 7, g = blk & 127;
  const int tid = threadIdx.x;

  for (int i = tid; i < 1536; i += 512) W0L110[i] = W0_110[i];
  for (int i = tid; i < 768; i += 512) W0L011[i] = W0_011[i];
  if (tid < 128) {
    W0L001[tid] = W0_001[tid];
    busum[tid] = b0_110[tid] + b0_110[128 + tid] + b0_110[256 + tid]
               + b0_011[256 + tid];
    bvsum[tid] = b0_011[tid] + b0_011[128 + tid] + b0_001[tid];
    mpu[tid] = maxpU0g[(b * 128 + tid) * 128 + g];
    mev[tid] = maxeV0g[(b * 128 + tid) * 128 + g];
  } else if (tid >= 256 && tid < 448) {
    int i = tid - 256;
    int c = i / 96, e = i % 96;
    x011row[i] = x011[((size_t)(b * 2 + c) * 128 + g) * 96 + e];
    rmg011s[i] = rmg011G[b * 192 + i];
  } else if (tid >= 448 && tid < 512) {
    int i = tid - 448;
    int c = i >> 4, p = i & 15;
    x110col[i] = x110[((size_t)(b * 4 + c) * 16 + p) * 128 + g];
    rmg110p[i] = rmgG[b * 64 + i];
  } else if (tid >= 128 && tid < 224) {
    x001s[tid - 128] = x001[b * 96 + tid - 128];
  } else if (tid >= 224 && tid < 228) {
    rmp4[tid - 224] = rmpG[(b * 4 + tid - 224) * 128 + g];
  } else if (tid >= 228 && tid < 230) {
    rme2[tid - 228] = rmeG[(b * 2 + tid - 228) * 128 + g];
  }
  __syncthreads();

  // s110 column (c,p) at this g
#pragma unroll
  for (int k = 0; k < 4; k++) {
    int i = tid + k * 512, c = i >> 4, p = i & 15;
    float acc = busum[c] + W0L011[512 + c * 2] * rme2[0]
              + W0L011[512 + c * 2 + 1] * rme2[1];
#pragma unroll
    for (int cc = 0; cc < 4; cc++)
      acc += W0L110[c * 4 + cc] * x110col[cc * 16 + p]
           + W0L110[512 + c * 4 + cc] * rmp4[cc]
           + W0L110[1024 + c * 4 + cc] * rmg110p[cc * 16 + p];
    s110c[i] = lrelu(acc + mev[c]);
  }
  // s011 column (c,e) at this g
  for (int k = 0; k < 24; k++) {
    int i = tid + k * 512;
    int c = i / 96, e = i - c * 96;
    float v = bvsum[c]
            + W0L011[c * 2] * x011row[e] + W0L011[c * 2 + 1] * x011row[96 + e]
            + W0L011[256 + c * 2] * rmg011s[e]
            + W0L011[256 + c * 2 + 1] * rmg011s[96 + e]
            + W0L001[c] * x001s[e];
    s011c[i] = lrelu(v + mpu[c]);
  }
  __syncthreads();

  const float* w0T = wT;
  const float* w3T = wT + 3 * 16384;

  // ---- U1part: n = tid&127 (lane-contiguous), ph = tid>>7 (0..3), 4 p each
  {
    int n = tid & 127, ph = tid >> 7;
    float a[4] = {0.f, 0.f, 0.f, 0.f};
    for (int c = 0; c < 128; c++) {
      float w0v = w0T[c * 128 + n];
      float4 s = *(const float4*)&s110c[c * 16 + ph * 4];
      a[0] += w0v * s.x; a[1] += w0v * s.y; a[2] += w0v * s.z; a[3] += w0v * s.w;
    }
    float* dst = U1 + ((size_t)((b * 128 + g) * 16 + ph * 4)) * 128 + n;
#pragma unroll
    for (int j = 0; j < 4; j++) dst[j * 128] = a[j];
  }
  // ---- V1part: 2n x 12e per thread
  {
    int n0 = (tid >> 3) * 2, e0 = (tid & 7) * 12;
    float4 aA[3], aB[3];
#pragma unroll
    for (int k = 0; k < 3; k++) {
      aA[k] = make_float4(0.f, 0.f, 0.f, 0.f);
      aB[k] = make_float4(0.f, 0.f, 0.f, 0.f);
    }
    for (int c = 0; c < 128; c++) {
      float2 wv = *(const float2*)&w3T[c * 128 + n0];
      float4 s0 = *(const float4*)&s011c[c * 96 + e0];
      float4 s1 = *(const float4*)&s011c[c * 96 + e0 + 4];
      float4 s2 = *(const float4*)&s011c[c * 96 + e0 + 8];
      aA[0].x += wv.x * s0.x; aA[0].y += wv.x * s0.y;
      aA[0].z += wv.x * s0.z; aA[0].w += wv.x * s0.w;
      aA[1].x += wv.x * s1.x; aA[1].y += wv.x * s1.y;
      aA[1].z += wv.x * s1.z; aA[1].w += wv.x * s1.w;
      aA[2].x += wv.x * s2.x; aA[2].y += wv.x * s2.y;
      aA[2].z += wv.x * s2.z; aA[2].w += wv.x * s2.w;
      aB[0].x += wv.y * s0.x; aB[0].y += wv.y * s0.y;
      aB[0].z += wv.y * s0.z; aB[0].w += wv.y * s0.w;
      aB[1].x += wv.y * s1.x; aB[1].y += wv.y * s1.y;
      aB[1].z += wv.y * s1.z; aB[1].w += wv.y * s1.w;
      aB[2].x += wv.y * s2.x; aB[2].y += wv.y * s2.y;
      aB[2].z += wv.y * s2.z; aB[2].w += wv.y * s2.w;
    }
    float* dA = V1 + ((size_t)((b * 128 + g) * 128 + n0)) * 96 + e0;
    float* dB = dA + 96;
#pragma unroll
    for (int k = 0; k < 3; k++) {
      *(float4*)(dA + k * 4) = aA[k];
      *(float4*)(dB + k * 4) = aB[k];
    }
  }
}

// ---------------------------------------------------------------------------
// K3: per-(b,n) reduction to head inputs + g-independent bias terms.
__global__ void __launch_bounds__(256) k_post1b(
    const float* __restrict__ U1, const float* __restrict__ V1,
    const float* __restrict__ s001a, const float* __restrict__ mp110,
    const float* __restrict__ mg110,
    const float* __restrict__ wT, const float* __restrict__ b1,
    float* __restrict__ m110, float* __restrict__ m011e,
    float* __restrict__ s001b) {
  __shared__ float vrow[128 * 97];
  __shared__ float uU[16 * 128];
  __shared__ float part[256];
  __shared__ float smaxeV[128], smaxpU[128];
  __shared__ float bf[128], eg[96], cp[16];
  const int bn = blockIdx.x, b = bn >> 7, n = bn & 127;
  const int tid = threadIdx.x;
  const float* w15T = wT + 16384;
  const float* w2T  = wT + 2 * 16384;
  const float* w46T = wT + 4 * 16384;

  // phase 0: g-independent additive terms (inputs L2-hot, shared across blocks)
  if (tid < 128) {
    float acc = 0.f;
    for (int c = 0; c < 128; c++)
      acc += w15T[c * 128 + n] * mp110[(b * 128 + c) * 128 + tid];
    bf[tid] = acc;
  } else if (tid < 224) {
    int e = tid - 128;
    float acc = 0.f;
    for (int c = 0; c < 128; c++)
      acc += w46T[c * 128 + n] * s001a[b * 12288 + c * 96 + e];
    eg[e] = acc;
  } else if (tid < 240) {
    int p = tid - 224;
    float acc = 0.f;
    for (int c = 0; c < 128; c++)
      acc += w2T[c * 128 + n] * mg110[(b * 128 + c) * 16 + p];
    cp[p] = acc;
  }
  __syncthreads();
  const float bb = b1[n] + b1[128 + n] + b1[256 + n] + b1[640 + n];
  const float bv = b1[384 + n] + b1[512 + n] + b1[768 + n];

  for (int i = tid; i < 2048; i += 256) {
    int p = i >> 7, g = i & 127;
    uU[i] = U1[((size_t)((b * 128 + g) * 16 + p)) * 128 + n] + bb + cp[p] + bf[g];
  }
#pragma unroll
  for (int k = 0; k < 12; k++) {
    int i4 = tid + k * 256;
    int g = i4 / 24, e4 = i4 - g * 24;
    float4 v = *(const float4*)(V1 + ((size_t)((b * 128 + g) * 128 + n)) * 96 + e4 * 4);
    float* d = &vrow[g * 97 + e4 * 4];
    d[0] = v.x + bv + eg[e4 * 4];
    d[1] = v.y + bv + eg[e4 * 4 + 1];
    d[2] = v.z + bv + eg[e4 * 4 + 2];
    d[3] = v.w + bv + eg[e4 * 4 + 3];
  }
  __syncthreads();
  {
    int g = tid & 127, h = tid >> 7;
    const float* r = &vrow[g * 97 + h * 48];
    float m = -INFINITY;
    for (int j = 0; j < 48; j++) m = fmaxf(m, r[j]);
    part[tid] = m;
  }
  __syncthreads();
  if (tid < 128) {
    smaxeV[tid] = fmaxf(part[tid], part[tid + 128]);
    float mp = -INFINITY;
    for (int p = 0; p < P; p++) mp = fmaxf(mp, uU[p * 128 + tid]);
    smaxpU[tid] = mp;
  }
  __syncthreads();
  if (tid >= 128 && tid < 144) {
    int p = tid - 128;
    float s = 0.f;
    for (int g = 0; g < G; g++)
      s += lrelu(uU[p * 128 + g] + smaxeV[g]);
    m110[bn * 16 + p] = s * (1.f / G);
  }
  if (tid < 96) {
    float s = 0.f, mm = -INFINITY;
    for (int g = 0; g < G; g++) {
      float pre = smaxpU[g] + vrow[g * 97 + tid];
      s += lrelu(pre);
      mm = fmaxf(mm, pre);
    }
    m011e[bn * 96 + tid] = s * (1.f / G);
    s001b[bn * 96 + tid] = lrelu(mm);
  }
}

// ---------------------------------------------------------------------------
// K4: heads. one block per (b,o), 128 threads.  [proven]
__global__ void __launch_bounds__(128) k_final(const float* __restrict__ m110,
                                               const float* __restrict__ m011e,
                                               const float* __restrict__ s001,
                                               const float* __restrict__ Wact,
                                               const float* __restrict__ bact,
                                               const float* __restrict__ Wcrit,
                                               const float* __restrict__ bcrit,
                                               float* __restrict__ out) {
  __shared__ float sm011[N], sm001[N], scp[P], sce[E], srow[P], scol[E];
  const int bo = blockIdx.x;
  const int o = bo & 1, b = bo >> 1;
  const int t = threadIdx.x;
  {
    float s1 = 0.f, s2 = 0.f;
    const float* p1 = m011e + (b * N + t) * E;
    const float* p2 = s001 + (b * N + t) * E;
    for (int e = 0; e < E; e++) { s1 += p1[e]; s2 += p2[e]; }
    sm011[t] = s1 * (1.f / E);
    sm001[t] = s2 * (1.f / E);
  }
  __syncthreads();
  if (t < P) {
    const float* wa0 = Wact + o * N;
    const float* wa1 = Wact + (1 * CO + o) * N;
    const float* wa2 = Wact + (2 * CO + o) * N;
    const float* wc0 = Wcrit + o * N;
    float a = 0.f, c = 0.f, aa = 0.f;
    for (int n = 0; n < N; n++) {
      float m = m110[(b * N + n) * P + t];
      a += wa0[n] * m;
      c += wc0[n] * m;
      aa += wa1[n] * sm011[n] + wa2[n] * sm001[n];
    }
    float act = a + aa + bact[o] + bact[CO + o] + bact[2 * CO + o];
    out[(b * CO + o) * P + t] = lrelu(act);
    scp[t] = c + bcrit[o];
  } else if (t < P + E) {
    int e = t - P;
    const float* wc1 = Wcrit + (1 * CO + o) * N;
    const float* wc2 = Wcrit + (2 * CO + o) * N;
    float c = 0.f;
    for (int n = 0; n < N; n++)
      c += wc1[n] * m011e[(b * N + n) * E + e] + wc2[n] * s001[(b * N + n) * E + e];
    sce[e] = c + bcrit[CO + o] + bcrit[2 * CO + o];
  }
  __syncthreads();
  if (t < P) {
    float m = -INFINITY;
    for (int e = 0; e < E; e++) m = fmaxf(m, lrelu(scp[t] + sce[e]));
    srow[t] = m;
  } else if (t < P + E) {
    int e = t - P;
    float m = -INFINITY;
    for (int p = 0; p < P; p++) m = fmaxf(m, lrelu(scp[p] + sce[e]));
    scol[e] = m;
  }
  __syncthreads();
  if (t == 0) {
    float v110 = 0.f, v011 = 0.f;
    for (int p = 0; p < P; p++) v110 += srow[p];
    for (int e = 0; e < E; e++) v011 += scol[e];
    out[B * CO * P + b * CO + o] = 2.f + v110 + 2.f * v011;
  }
}

extern "C" void kernel_launch(void* const* d_in, const int* in_sizes, int n_in,
                              void* d_out, int out_size, void* d_ws, size_t ws_size,
                              hipStream_t stream) {
  const float* x110   = (const float*)d_in[0];
  const float* x011   = (const float*)d_in[1];
  const float* x001   = (const float*)d_in[2];
  const float* W0_110 = (const float*)d_in[3];
  const float* b0_110 = (const float*)d_in[4];
  const float* W0_011 = (const float*)d_in[5];
  const float* b0_011 = (const float*)d_in[6];
  const float* W0_001 = (const float*)d_in[7];
  const float* b0_001 = (const float*)d_in[8];
  const float* W1     = (const float*)d_in[9];
  const float* b1     = (const float*)d_in[10];
  const float* Wact   = (const float*)d_in[11];
  const float* bact   = (const float*)d_in[12];
  const float* Wcrit  = (const float*)d_in[13];
  const float* bcrit  = (const float*)d_in[14];
  float* out = (float*)d_out;
  float* w = (float*)d_ws;

  float* U1     = w + OFF_U1;
  float* V1     = w + OFF_V1;
  float* maxpU0 = w + OFF_MAXPU0;
  float* maxeV0 = w + OFF_MAXEV0;
  float* mp110  = w + OFF_MP110;
  float* mg110  = w + OFF_MG110;
  float* s001a  = w + OFF_S001A;
  float* rmpG   = w + OFF_RMP;
  float* rmgG   = w + OFF_RMG;
  float* rmeG   = w + OFF_RME;
  float* rmg011 = w + OFF_RMG011;
  float* m110   = w + OFF_M110;
  float* m011e  = w + OFF_M011E;
  float* s001b  = w + OFF_S001B;
  float* wT     = w + OFF_WT;

  k_layer0<<<256, 256, 0, stream>>>(x110, x011, x001, W0_110, b0_110, W0_011,
                                    b0_011, W0_001, b0_001, W1,
                                    maxpU0, maxeV0, mp110, mg110, s001a,
                                    rmpG, rmgG, rmeG, rmg011, wT);
  k_layer1c<<<256, 512, 0, stream>>>(x110, x011, x001, W0_110, b0_110, W0_011,
                                     b0_011, W0_001, b0_001,
                                     maxpU0, maxeV0, rmpG, rmgG, rmeG, rmg011,
                                     wT, U1, V1);
  k_post1b<<<256, 256, 0, stream>>>(U1, V1, s001a, mp110, mg110, wT, b1,
                                    m110, m011e, s001b);
  k_final<<<4, 128, 0, stream>>>(m110, m011e, s001b, Wact, bact, Wcrit, bcrit, out);
}